// Round 2
// baseline (497.416 us; speedup 1.0000x reference)
//
#include <hip/hip_runtime.h>
#include <math.h>

#define Bn 4
#define Tn 4096
#define Dn 1024
#define Nn 64
#define Rn 16
#define KCONV 4

#define KC 32     // K-chunk for prep GEMM
#define TT 64     // t-rows per prep block
#define SU 32     // scan unroll / prefetch depth

// Layout trick: intermediates live INSIDE d_out rows (row bt = 1024 floats):
//   cols [0,64)    P  (projected)   written by prep, read by scan
//   cols [64,128)  Dl (delta)       written by prep, read by scan
//   cols [128,192) S  (scan states) written by scan, read by out_kernel
// out_kernel loads its own rows' S to LDS before overwriting the full rows,
// and no block touches another block's rows -> race-free, zero d_ws usage.

// ---------------------------------------------------------------------------
// Kernel 1: fused causal depthwise conv + input projection + delta projection.
// grid (T/TT, B), block 512.
// ---------------------------------------------------------------------------
__global__ __launch_bounds__(512)
void prep_kernel(const float* __restrict__ x, const float* __restrict__ conv_w,
                 const float* __restrict__ in_w, const float* __restrict__ in_b,
                 const float* __restrict__ dt_w, const float* __restrict__ dt_b,
                 const float* __restrict__ tr_w,
                 float* __restrict__ O)
{
    __shared__ float xs[TT + 3][KC + 4];   // raw x rows t0-3 .. t0+TT-1
    __shared__ float xcs[TT][KC + 4];      // x + conv(x)
    __shared__ float ws[KC][Nn + 4];       // ws[k][n] = in_w[n][k0+k]
    __shared__ float dwsT[Rn][KC + 4];     // dwsT[r][k] = dt_w[r][k0+k]
    __shared__ float cwT[KCONV][KC];       // cwT[j][d_local]
    __shared__ float trS[Nn * 17];         // tr_w padded stride 17
    __shared__ float As[TT][Rn + 4];       // tanh activations

    const int tid = threadIdx.x;
    const int b   = blockIdx.y;
    const int t0  = blockIdx.x * TT;
    const int c   = tid & 15;   // col group: proj cols 4c..4c+3, delta row r=c
    const int g   = tid >> 4;   // 0..31 -> rows {g, g+32}

    const float* xb = x + (size_t)b * Tn * Dn;

    for (int idx = tid; idx < Nn * Rn; idx += 512) {
        int n = idx >> 4, r = idx & 15;
        trS[n * 17 + r] = tr_w[idx];
    }

    float acc_p[2][4] = {};
    float acc_d[2]    = {};

    for (int kc = 0; kc < Dn / KC; ++kc) {
        const int k0 = kc * KC;
        __syncthreads();   // previous iteration's reads done before restage

        for (int idx = tid; idx < (TT + 3) * KC; idx += 512) {
            int row = idx / KC, col = idx - row * KC;
            int t = t0 - 3 + row;
            xs[row][col] = (t >= 0) ? xb[t * Dn + k0 + col] : 0.f;
        }
        for (int idx = tid; idx < Nn * KC; idx += 512) {
            int n = idx / KC, k = idx - n * KC;
            ws[k][n] = in_w[n * Dn + k0 + k];
        }
        for (int idx = tid; idx < Rn * KC; idx += 512) {
            int r = idx / KC, k = idx - r * KC;
            dwsT[r][k] = dt_w[r * Dn + k0 + k];
        }
        if (tid < KC * KCONV) {
            int d = tid >> 2, j = tid & 3;
            cwT[j][d] = conv_w[(k0 + d) * KCONV + j];
        }
        __syncthreads();

        // xc[t] = x[t] + sum_j x[t-3+j]*cw[j]
        for (int idx = tid; idx < TT * KC; idx += 512) {
            int row = idx / KC, col = idx - row * KC;
            float v = xs[row + 3][col];
            v = fmaf(xs[row + 0][col], cwT[0][col], v);
            v = fmaf(xs[row + 1][col], cwT[1][col], v);
            v = fmaf(xs[row + 2][col], cwT[2][col], v);
            v = fmaf(xs[row + 3][col], cwT[3][col], v);
            xcs[row][col] = v;
        }
        __syncthreads();

        #pragma unroll
        for (int kq = 0; kq < KC; kq += 4) {
            float4 wv0 = *(const float4*)&ws[kq + 0][4 * c];
            float4 wv1 = *(const float4*)&ws[kq + 1][4 * c];
            float4 wv2 = *(const float4*)&ws[kq + 2][4 * c];
            float4 wv3 = *(const float4*)&ws[kq + 3][4 * c];
            float4 dv  = *(const float4*)&dwsT[c][kq];
            #pragma unroll
            for (int i = 0; i < 2; ++i) {
                int row = g + 32 * i;
                float4 xv = *(const float4*)&xcs[row][kq];
                float4 rv = *(const float4*)&xs[row + 3][kq];
                acc_p[i][0] = fmaf(xv.x, wv0.x, fmaf(xv.y, wv1.x, fmaf(xv.z, wv2.x, fmaf(xv.w, wv3.x, acc_p[i][0]))));
                acc_p[i][1] = fmaf(xv.x, wv0.y, fmaf(xv.y, wv1.y, fmaf(xv.z, wv2.y, fmaf(xv.w, wv3.y, acc_p[i][1]))));
                acc_p[i][2] = fmaf(xv.x, wv0.z, fmaf(xv.y, wv1.z, fmaf(xv.z, wv2.z, fmaf(xv.w, wv3.z, acc_p[i][2]))));
                acc_p[i][3] = fmaf(xv.x, wv0.w, fmaf(xv.y, wv1.w, fmaf(xv.z, wv2.w, fmaf(xv.w, wv3.w, acc_p[i][3]))));
                acc_d[i]    = fmaf(rv.x, dv.x,  fmaf(rv.y, dv.y,  fmaf(rv.z, dv.z,  fmaf(rv.w, dv.w,  acc_d[i]))));
            }
        }
    }

    __syncthreads();
    #pragma unroll
    for (int i = 0; i < 2; ++i) {
        int row = g + 32 * i;
        As[row][c] = tanhf(acc_d[i] + dt_b[c]);
    }
    __syncthreads();

    #pragma unroll
    for (int i = 0; i < 2; ++i) {
        int row = g + 32 * i;
        float a[16];
        #pragma unroll
        for (int r = 0; r < 16; ++r) a[r] = As[row][r];
        float pj[4], dj[4];
        #pragma unroll
        for (int j = 0; j < 4; ++j) {
            int n = 4 * c + j;
            const float* trp = &trS[n * 17];
            float s = 0.f;
            #pragma unroll
            for (int r = 0; r < 16; ++r) s = fmaf(a[r], trp[r], s);
            dj[j] = s;
            pj[j] = acc_p[i][j] + in_b[n];
        }
        // write into d_out row: P at cols [0,64), Dl at cols [64,128)
        size_t base = ((size_t)(b * Tn + t0 + row)) * Dn + 4 * c;
        *(float4*)&O[base]      = make_float4(pj[0], pj[1], pj[2], pj[3]);
        *(float4*)&O[base + 64] = make_float4(dj[0], dj[1], dj[2], dj[3]);
    }
}

// ---------------------------------------------------------------------------
// Kernel 2: the sequential scan. 256 independent (b,n) chains.
// grid (B), block 64 (one lane per n). Software-pipelined: prefetch next
// SU-step chunk of P/Dl into registers while chewing the serial silu chain.
// state = silu(delta + state) + projected
// ---------------------------------------------------------------------------
__global__ __launch_bounds__(64)
void scan_kernel(float* __restrict__ O)
{
    const int b = blockIdx.x;
    const int n = threadIdx.x;
    float* base = O + (size_t)b * Tn * Dn;

    const float L2E = 1.44269504088896340736f;
    float pc[SU], dc[SU], pn[SU], dn_[SU];

    #pragma unroll
    for (int i = 0; i < SU; ++i) {
        pc[i]  = base[(size_t)i * Dn + n];
        dc[i]  = base[(size_t)i * Dn + 64 + n];
    }

    float st = 0.f;
    for (int t0 = 0; t0 < Tn; t0 += SU) {
        const bool more = (t0 + SU) < Tn;
        if (more) {
            float* nb = base + (size_t)(t0 + SU) * Dn;
            #pragma unroll
            for (int i = 0; i < SU; ++i) {
                pn[i]  = nb[(size_t)i * Dn + n];
                dn_[i] = nb[(size_t)i * Dn + 64 + n];
            }
        }
        float* cb = base + (size_t)t0 * Dn;
        #pragma unroll
        for (int i = 0; i < SU; ++i) {
            // chain: fma -> exp2 -> add -> rcp -> fma  (u's add is off-chain)
            float dL = dc[i] * L2E;                       // independent
            float u  = st + dc[i];                        // parallel branch
            float e  = __builtin_amdgcn_exp2f(fmaf(st, -L2E, -dL));
            float r  = __builtin_amdgcn_rcpf(1.f + e);
            st = fmaf(u, r, pc[i]);
            cb[(size_t)i * Dn + 128 + n] = st;            // S at cols [128,192)
        }
        if (more) {
            #pragma unroll
            for (int i = 0; i < SU; ++i) { pc[i] = pn[i]; dc[i] = dn_[i]; }
        }
    }
}

// ---------------------------------------------------------------------------
// Kernel 3: output projection, in-place over d_out.
// grid (BT/64): ONE block per 64-row tile computes ALL 1024 columns.
// Loads its own rows' S (cols [128,192)) into LDS first, then overwrites.
// ---------------------------------------------------------------------------
__global__ __launch_bounds__(256)
void out_kernel(const float* __restrict__ out_w, const float* __restrict__ out_b,
                float* __restrict__ O)
{
    __shared__ float Ss[64][Nn + 4];
    __shared__ float wT[Nn][64 + 4];   // wT[n][d_local] for current 64-col chunk

    const int tid = threadIdx.x;
    const int r0  = blockIdx.x * 64;
    const int c   = tid & 15;   // cols 4c..4c+3 within chunk
    const int g   = tid >> 4;   // rows {g, g+16, g+32, g+48}

    // load this block's S rows into LDS BEFORE any global writes
    for (int idx = tid; idx < 64 * Nn / 4; idx += 256) {
        int row = idx >> 4, n4 = (idx & 15) * 4;
        *(float4*)&Ss[row][n4] =
            *(const float4*)&O[(size_t)(r0 + row) * Dn + 128 + n4];
    }
    __syncthreads();

    for (int cb = 0; cb < Dn / 64; ++cb) {
        const int d0 = cb * 64;
        for (int idx = tid; idx < Nn * 64 / 4; idx += 256) {
            int dl = idx >> 4, n4 = (idx & 15) * 4;
            float4 w = *(const float4*)&out_w[(size_t)(d0 + dl) * Nn + n4];
            wT[n4 + 0][dl] = w.x;
            wT[n4 + 1][dl] = w.y;
            wT[n4 + 2][dl] = w.z;
            wT[n4 + 3][dl] = w.w;
        }
        __syncthreads();

        float acc[4][4] = {};
        #pragma unroll
        for (int kq = 0; kq < Nn; kq += 4) {
            float4 wv0 = *(const float4*)&wT[kq + 0][4 * c];
            float4 wv1 = *(const float4*)&wT[kq + 1][4 * c];
            float4 wv2 = *(const float4*)&wT[kq + 2][4 * c];
            float4 wv3 = *(const float4*)&wT[kq + 3][4 * c];
            #pragma unroll
            for (int i = 0; i < 4; ++i) {
                int row = g + 16 * i;
                float4 xv = *(const float4*)&Ss[row][kq];
                acc[i][0] = fmaf(xv.x, wv0.x, fmaf(xv.y, wv1.x, fmaf(xv.z, wv2.x, fmaf(xv.w, wv3.x, acc[i][0]))));
                acc[i][1] = fmaf(xv.x, wv0.y, fmaf(xv.y, wv1.y, fmaf(xv.z, wv2.y, fmaf(xv.w, wv3.y, acc[i][1]))));
                acc[i][2] = fmaf(xv.x, wv0.z, fmaf(xv.y, wv1.z, fmaf(xv.z, wv2.z, fmaf(xv.w, wv3.z, acc[i][2]))));
                acc[i][3] = fmaf(xv.x, wv0.w, fmaf(xv.y, wv1.w, fmaf(xv.z, wv2.w, fmaf(xv.w, wv3.w, acc[i][3]))));
            }
        }

        float4 bb = *(const float4*)&out_b[d0 + 4 * c];
        #pragma unroll
        for (int i = 0; i < 4; ++i) {
            int row = g + 16 * i;
            float4 o = make_float4(acc[i][0] + bb.x, acc[i][1] + bb.y,
                                   acc[i][2] + bb.z, acc[i][3] + bb.w);
            *(float4*)&O[(size_t)(r0 + row) * Dn + d0 + 4 * c] = o;
        }
        __syncthreads();   // reads of wT done before next chunk restages
    }
}

extern "C" void kernel_launch(void* const* d_in, const int* in_sizes, int n_in,
                              void* d_out, int out_size, void* d_ws, size_t ws_size,
                              hipStream_t stream)
{
    const float* x      = (const float*)d_in[0];
    const float* conv_w = (const float*)d_in[1];
    const float* in_w   = (const float*)d_in[2];
    const float* in_b   = (const float*)d_in[3];
    const float* dt_w   = (const float*)d_in[4];
    const float* dt_b   = (const float*)d_in[5];
    const float* tr_w   = (const float*)d_in[6];
    const float* out_w  = (const float*)d_in[7];
    const float* out_b  = (const float*)d_in[8];
    float* O = (float*)d_out;
    (void)d_ws; (void)ws_size;   // d_ws proved too small in R1 — unused now

    dim3 g1(Tn / TT, Bn);
    prep_kernel<<<g1, 512, 0, stream>>>(x, conv_w, in_w, in_b, dt_w, dt_b, tr_w, O);

    scan_kernel<<<dim3(Bn), 64, 0, stream>>>(O);

    out_kernel<<<dim3((Bn * Tn) / 64), 256, 0, stream>>>(out_w, out_b, O);
}

// Round 3
// 424.301 us; speedup vs baseline: 1.1723x; 1.1723x over previous
//
#include <hip/hip_runtime.h>
#include <math.h>

#define Bn 4
#define Tn 4096
#define Dn 1024
#define Nn 64
#define Rn 16
#define KCONV 4

#define TT2 32    // t-rows per prep block (grid = 128*4 = 512 blocks, 2/CU)
#define KCH 32    // K-chunk (one 16x16x32 MFMA K-step)
#define SU 32     // scan unroll / prefetch depth
#define OT 64     // rows per out block

typedef __attribute__((ext_vector_type(8))) short bf16x8;
typedef __attribute__((ext_vector_type(4))) float f32x4;

__device__ __forceinline__ unsigned short bf16_rne(float f) {
    unsigned int u = __float_as_uint(f);
    unsigned int r = (u + 0x7fffu + ((u >> 16) & 1u)) >> 16;
    return (unsigned short)r;
}

// Layout trick: intermediates live INSIDE d_out rows (row bt = 1024 floats):
//   cols [0,64)    P  (projected)   written by prep, read by scan
//   cols [64,128)  Dl (delta)       written by prep, read by scan
//   cols [128,192) S  (scan states) written by scan, read by out_kernel
// out_kernel loads its own rows' S to LDS before overwriting the full rows.

// ---------------------------------------------------------------------------
// Kernel 1 (MFMA bf16x3): fused conv + input proj + delta path.
// grid (T/32, B), block 128 (2 waves; wave w owns 16-row M-tile).
// P  = (x+conv(x)) @ in_w.T + in_b        [via 3-MFMA hi/lo fp32-emulation]
// G  = x @ dt_w.T  -> As = tanh(G+dt_b) -> Dl = As @ tr_w.T  [tiny, VALU]
// ---------------------------------------------------------------------------
__global__ __launch_bounds__(128)
void prep_kernel(const float* __restrict__ x, const float* __restrict__ conv_w,
                 const float* __restrict__ in_w, const float* __restrict__ in_b,
                 const float* __restrict__ dt_w, const float* __restrict__ dt_b,
                 const float* __restrict__ tr_w,
                 float* __restrict__ O)
{
    // MFMA fragment arrays: frag = 8 contiguous k-elems; lane = (row&15)|(koct<<4)
    __shared__ bf16x8 Axc_h[2][64], Axc_l[2][64];   // A = x+conv (hi/lo)
    __shared__ bf16x8 Axr_h[2][64], Axr_l[2][64];   // A = raw x  (hi/lo)
    __shared__ bf16x8 Bw_h[4][64],  Bw_l[4][64];    // B = in_w rows (hi/lo)
    __shared__ bf16x8 Bd_h[64],     Bd_l[64];       // B = dt_w rows (hi/lo)
    __shared__ float  AsS[TT2][17];                 // tanh activations
    __shared__ float  trS[Nn][17];                  // tr_w padded

    const int tid = threadIdx.x;
    const int b   = blockIdx.y;
    const int t0  = blockIdx.x * TT2;
    const int l   = tid & 63;
    const int w   = tid >> 6;          // wave id = M-tile id (rows 16w..16w+15)

    const float* xb = x + (size_t)b * Tn * Dn;

    for (int idx = tid; idx < Nn * Rn; idx += 128)
        trS[idx >> 4][idx & 15] = tr_w[idx];

    const f32x4 z4 = {0.f, 0.f, 0.f, 0.f};
    f32x4 accP[4] = {z4, z4, z4, z4};
    f32x4 accG = z4;

    for (int kc = 0; kc < Dn / KCH; ++kc) {
        const int k0 = kc * KCH;
        __syncthreads();   // prior chunk's fragment reads complete

        // ---- stage A fragments: conv + hi/lo split, 1 (row,k-seg) per thread
        {
            const int m  = tid & 31;
            const int s  = tid >> 5;          // k-oct (8 k's)
            const int t  = t0 + m;
            const int gk = k0 + 8 * s;
            float v[4][8];
            #pragma unroll
            for (int dr = 0; dr < 4; ++dr) {
                int tp = t - 3 + dr;
                if (tp >= 0) {
                    float4 a  = *(const float4*)&xb[(size_t)tp * Dn + gk];
                    float4 bq = *(const float4*)&xb[(size_t)tp * Dn + gk + 4];
                    v[dr][0]=a.x;  v[dr][1]=a.y;  v[dr][2]=a.z;  v[dr][3]=a.w;
                    v[dr][4]=bq.x; v[dr][5]=bq.y; v[dr][6]=bq.z; v[dr][7]=bq.w;
                } else {
                    #pragma unroll
                    for (int k = 0; k < 8; ++k) v[dr][k] = 0.f;
                }
            }
            bf16x8 fch, fcl, frh, frl;
            #pragma unroll
            for (int k = 0; k < 8; ++k) {
                float4 cw = *(const float4*)&conv_w[(size_t)(gk + k) * 4];
                float xr = v[3][k];
                float xc = xr;
                xc = fmaf(v[0][k], cw.x, xc);
                xc = fmaf(v[1][k], cw.y, xc);
                xc = fmaf(v[2][k], cw.z, xc);
                xc = fmaf(v[3][k], cw.w, xc);
                unsigned short h; float hf;
                h = bf16_rne(xc); hf = __uint_as_float((unsigned)h << 16);
                fch[k] = (short)h; fcl[k] = (short)bf16_rne(xc - hf);
                h = bf16_rne(xr); hf = __uint_as_float((unsigned)h << 16);
                frh[k] = (short)h; frl[k] = (short)bf16_rne(xr - hf);
            }
            const int lane = (m & 15) | (s << 4), mt = m >> 4;
            Axc_h[mt][lane] = fch; Axc_l[mt][lane] = fcl;
            Axr_h[mt][lane] = frh; Axr_l[mt][lane] = frl;
        }
        // ---- stage B fragments: in_w (2 slots/thread), dt_w (threads 0-63)
        #pragma unroll
        for (int rep = 0; rep < 2; ++rep) {
            int slot = tid + rep * 128;
            int n = slot & 63, s = slot >> 6;
            const float* wp = &in_w[(size_t)n * Dn + k0 + 8 * s];
            float4 a  = *(const float4*)wp;
            float4 bq = *(const float4*)(wp + 4);
            float wv[8] = {a.x, a.y, a.z, a.w, bq.x, bq.y, bq.z, bq.w};
            bf16x8 fh, fl;
            #pragma unroll
            for (int k = 0; k < 8; ++k) {
                unsigned short h = bf16_rne(wv[k]);
                float hf = __uint_as_float((unsigned)h << 16);
                fh[k] = (short)h; fl[k] = (short)bf16_rne(wv[k] - hf);
            }
            Bw_h[n >> 4][(n & 15) | (s << 4)] = fh;
            Bw_l[n >> 4][(n & 15) | (s << 4)] = fl;
        }
        if (tid < 64) {
            int r = tid & 15, s = tid >> 4;
            const float* wp = &dt_w[(size_t)r * Dn + k0 + 8 * s];
            float4 a  = *(const float4*)wp;
            float4 bq = *(const float4*)(wp + 4);
            float wv[8] = {a.x, a.y, a.z, a.w, bq.x, bq.y, bq.z, bq.w};
            bf16x8 fh, fl;
            #pragma unroll
            for (int k = 0; k < 8; ++k) {
                unsigned short h = bf16_rne(wv[k]);
                float hf = __uint_as_float((unsigned)h << 16);
                fh[k] = (short)h; fl[k] = (short)bf16_rne(wv[k] - hf);
            }
            Bd_h[tid] = fh; Bd_l[tid] = fl;
        }
        __syncthreads();

        // ---- MFMA phase: bf16x3 = Ah*Bh + Al*Bh + Ah*Bl
        bf16x8 axh = Axc_h[w][l], axl = Axc_l[w][l];
        bf16x8 arh = Axr_h[w][l], arl = Axr_l[w][l];
        #pragma unroll
        for (int nt = 0; nt < 4; ++nt) {
            bf16x8 bh = Bw_h[nt][l], bl = Bw_l[nt][l];
            accP[nt] = __builtin_amdgcn_mfma_f32_16x16x32_bf16(axh, bh, accP[nt], 0, 0, 0);
            accP[nt] = __builtin_amdgcn_mfma_f32_16x16x32_bf16(axl, bh, accP[nt], 0, 0, 0);
            accP[nt] = __builtin_amdgcn_mfma_f32_16x16x32_bf16(axh, bl, accP[nt], 0, 0, 0);
        }
        {
            bf16x8 bh = Bd_h[l], bl = Bd_l[l];
            accG = __builtin_amdgcn_mfma_f32_16x16x32_bf16(arh, bh, accG, 0, 0, 0);
            accG = __builtin_amdgcn_mfma_f32_16x16x32_bf16(arl, bh, accG, 0, 0, 0);
            accG = __builtin_amdgcn_mfma_f32_16x16x32_bf16(arh, bl, accG, 0, 0, 0);
        }
    }

    // ---- epilogue: As = tanh(G + dt_b); Dl = As @ tr_w.T; write P, Dl
    __syncthreads();
    #pragma unroll
    for (int i = 0; i < 4; ++i)
        AsS[16 * w + 4 * (l >> 4) + i][l & 15] = tanhf(accG[i] + dt_b[l & 15]);
    __syncthreads();

    float as_[4][16];
    #pragma unroll
    for (int i = 0; i < 4; ++i) {
        int mrow = 16 * w + 4 * (l >> 4) + i;
        #pragma unroll
        for (int j = 0; j < 4; ++j) {
            float4 q = *(const float4*)&AsS[mrow][4 * j];
            as_[i][4*j] = q.x; as_[i][4*j+1] = q.y;
            as_[i][4*j+2] = q.z; as_[i][4*j+3] = q.w;
        }
    }
    #pragma unroll
    for (int nt = 0; nt < 4; ++nt) {
        int n = 16 * nt + (l & 15);
        float tw[16];
        #pragma unroll
        for (int j = 0; j < 4; ++j) {
            float4 q = *(const float4*)&trS[n][4 * j];
            tw[4*j] = q.x; tw[4*j+1] = q.y; tw[4*j+2] = q.z; tw[4*j+3] = q.w;
        }
        float ib = in_b[n];
        #pragma unroll
        for (int i = 0; i < 4; ++i) {
            int mrow = 16 * w + 4 * (l >> 4) + i;
            float dlv = 0.f;
            #pragma unroll
            for (int r = 0; r < 16; ++r) dlv = fmaf(as_[i][r], tw[r], dlv);
            size_t base = ((size_t)(b * Tn + t0 + mrow)) * Dn + n;
            O[base]      = accP[nt][i] + ib;
            O[base + 64] = dlv;
        }
    }
}

// ---------------------------------------------------------------------------
// Kernel 2: the sequential scan (UNCHANGED from verified R2).
// ---------------------------------------------------------------------------
__global__ __launch_bounds__(64)
void scan_kernel(float* __restrict__ O)
{
    const int b = blockIdx.x;
    const int n = threadIdx.x;
    float* base = O + (size_t)b * Tn * Dn;

    const float L2E = 1.44269504088896340736f;
    float pc[SU], dc[SU], pn[SU], dn_[SU];

    #pragma unroll
    for (int i = 0; i < SU; ++i) {
        pc[i]  = base[(size_t)i * Dn + n];
        dc[i]  = base[(size_t)i * Dn + 64 + n];
    }

    float st = 0.f;
    for (int t0 = 0; t0 < Tn; t0 += SU) {
        const bool more = (t0 + SU) < Tn;
        if (more) {
            float* nb = base + (size_t)(t0 + SU) * Dn;
            #pragma unroll
            for (int i = 0; i < SU; ++i) {
                pn[i]  = nb[(size_t)i * Dn + n];
                dn_[i] = nb[(size_t)i * Dn + 64 + n];
            }
        }
        float* cb = base + (size_t)t0 * Dn;
        #pragma unroll
        for (int i = 0; i < SU; ++i) {
            float dL = dc[i] * L2E;
            float u  = st + dc[i];
            float e  = __builtin_amdgcn_exp2f(fmaf(st, -L2E, -dL));
            float r  = __builtin_amdgcn_rcpf(1.f + e);
            st = fmaf(u, r, pc[i]);
            cb[(size_t)i * Dn + 128 + n] = st;
        }
        if (more) {
            #pragma unroll
            for (int i = 0; i < SU; ++i) { pc[i] = pn[i]; dc[i] = dn_[i]; }
        }
    }
}

// ---------------------------------------------------------------------------
// Kernel 3: output projection, in-place over d_out (UNCHANGED from R2).
// ---------------------------------------------------------------------------
__global__ __launch_bounds__(256)
void out_kernel(const float* __restrict__ out_w, const float* __restrict__ out_b,
                float* __restrict__ O)
{
    __shared__ float Ss[64][Nn + 4];
    __shared__ float wT[Nn][64 + 4];

    const int tid = threadIdx.x;
    const int r0  = blockIdx.x * 64;
    const int c   = tid & 15;
    const int g   = tid >> 4;

    for (int idx = tid; idx < 64 * Nn / 4; idx += 256) {
        int row = idx >> 4, n4 = (idx & 15) * 4;
        *(float4*)&Ss[row][n4] =
            *(const float4*)&O[(size_t)(r0 + row) * Dn + 128 + n4];
    }
    __syncthreads();

    for (int cb = 0; cb < Dn / 64; ++cb) {
        const int d0 = cb * 64;
        for (int idx = tid; idx < Nn * 64 / 4; idx += 256) {
            int dl = idx >> 4, n4 = (idx & 15) * 4;
            float4 wv = *(const float4*)&out_w[(size_t)(d0 + dl) * Nn + n4];
            wT[n4 + 0][dl] = wv.x;
            wT[n4 + 1][dl] = wv.y;
            wT[n4 + 2][dl] = wv.z;
            wT[n4 + 3][dl] = wv.w;
        }
        __syncthreads();

        float acc[4][4] = {};
        #pragma unroll
        for (int kq = 0; kq < Nn; kq += 4) {
            float4 wv0 = *(const float4*)&wT[kq + 0][4 * c];
            float4 wv1 = *(const float4*)&wT[kq + 1][4 * c];
            float4 wv2 = *(const float4*)&wT[kq + 2][4 * c];
            float4 wv3 = *(const float4*)&wT[kq + 3][4 * c];
            #pragma unroll
            for (int i = 0; i < 4; ++i) {
                int row = g + 16 * i;
                float4 xv = *(const float4*)&Ss[row][kq];
                acc[i][0] = fmaf(xv.x, wv0.x, fmaf(xv.y, wv1.x, fmaf(xv.z, wv2.x, fmaf(xv.w, wv3.x, acc[i][0]))));
                acc[i][1] = fmaf(xv.x, wv0.y, fmaf(xv.y, wv1.y, fmaf(xv.z, wv2.y, fmaf(xv.w, wv3.y, acc[i][1]))));
                acc[i][2] = fmaf(xv.x, wv0.z, fmaf(xv.y, wv1.z, fmaf(xv.z, wv2.z, fmaf(xv.w, wv3.z, acc[i][2]))));
                acc[i][3] = fmaf(xv.x, wv0.w, fmaf(xv.y, wv1.w, fmaf(xv.z, wv2.w, fmaf(xv.w, wv3.w, acc[i][3]))));
            }
        }

        float4 bb = *(const float4*)&out_b[d0 + 4 * c];
        #pragma unroll
        for (int i = 0; i < 4; ++i) {
            int row = g + 16 * i;
            float4 o = make_float4(acc[i][0] + bb.x, acc[i][1] + bb.y,
                                   acc[i][2] + bb.z, acc[i][3] + bb.w);
            *(float4*)&O[(size_t)(r0 + row) * Dn + d0 + 4 * c] = o;
        }
        __syncthreads();
    }
}

extern "C" void kernel_launch(void* const* d_in, const int* in_sizes, int n_in,
                              void* d_out, int out_size, void* d_ws, size_t ws_size,
                              hipStream_t stream)
{
    const float* x      = (const float*)d_in[0];
    const float* conv_w = (const float*)d_in[1];
    const float* in_w   = (const float*)d_in[2];
    const float* in_b   = (const float*)d_in[3];
    const float* dt_w   = (const float*)d_in[4];
    const float* dt_b   = (const float*)d_in[5];
    const float* tr_w   = (const float*)d_in[6];
    const float* out_w  = (const float*)d_in[7];
    const float* out_b  = (const float*)d_in[8];
    float* O = (float*)d_out;
    (void)d_ws; (void)ws_size;

    dim3 g1(Tn / TT2, Bn);
    prep_kernel<<<g1, 128, 0, stream>>>(x, conv_w, in_w, in_b, dt_w, dt_b, tr_w, O);

    scan_kernel<<<dim3(Bn), 64, 0, stream>>>(O);

    out_kernel<<<dim3((Bn * Tn) / 64), 256, 0, stream>>>(out_w, out_b, O);
}

// Round 4
// 422.248 us; speedup vs baseline: 1.1780x; 1.0049x over previous
//
#include <hip/hip_runtime.h>
#include <math.h>

#define Bn 4
#define Tn 4096
#define Dn 1024
#define Nn 64
#define Rn 16
#define KCONV 4

#define TT2 32    // t-rows per prep block
#define KCH 32    // K-chunk (one 16x16x32 MFMA K-step)
#define SU 32     // scan chunk (steps per prefetch block)

typedef __attribute__((ext_vector_type(8))) short bf16x8;
typedef __attribute__((ext_vector_type(4))) float f32x4;

__device__ __forceinline__ unsigned short bf16_rne(float f) {
    unsigned int u = __float_as_uint(f);
    unsigned int r = (u + 0x7fffu + ((u >> 16) & 1u)) >> 16;
    return (unsigned short)r;
}

// Layout: intermediates live INSIDE d_out, TRANSPOSED per 64-row tile.
// For tile t0' = t & ~63 (64 consecutive t rows of one batch):
//   element (t, n) of P  -> O[(b*Tn + t0' + n)*Dn +   0 + (t - t0')]
//   element (t, n) of Dl -> O[(b*Tn + t0' + n)*Dn +  64 + (t - t0')]
//   element (t, n) of S  -> O[(b*Tn + t0' + n)*Dn + 128 + (t - t0')]
// Each scan lane (fixed n) thus reads/writes CONTIGUOUS floats over t ->
// float4 register prefetch survives. out_kernel still only touches its own
// 64 rows before overwriting them. Race-free, zero d_ws usage.

// ---------------------------------------------------------------------------
// Kernel 1 (MFMA bf16x3): fused conv + input proj + delta path.
// grid (T/32, B), block 128 (2 waves; wave w owns 16-row M-tile).
// ---------------------------------------------------------------------------
__global__ __launch_bounds__(128)
void prep_kernel(const float* __restrict__ x, const float* __restrict__ conv_w,
                 const float* __restrict__ in_w, const float* __restrict__ in_b,
                 const float* __restrict__ dt_w, const float* __restrict__ dt_b,
                 const float* __restrict__ tr_w,
                 float* __restrict__ O)
{
    __shared__ bf16x8 Axc_h[2][64], Axc_l[2][64];   // A = x+conv (hi/lo)
    __shared__ bf16x8 Axr_h[2][64], Axr_l[2][64];   // A = raw x  (hi/lo)
    __shared__ bf16x8 Bw_h[4][64],  Bw_l[4][64];    // B = in_w rows (hi/lo)
    __shared__ bf16x8 Bd_h[64],     Bd_l[64];       // B = dt_w rows (hi/lo)
    __shared__ float  AsS[TT2][17];                 // tanh activations
    __shared__ float  trS[Nn][17];                  // tr_w padded

    const int tid = threadIdx.x;
    const int b   = blockIdx.y;
    const int t0  = blockIdx.x * TT2;
    const int l   = tid & 63;
    const int w   = tid >> 6;

    const float* xb = x + (size_t)b * Tn * Dn;

    for (int idx = tid; idx < Nn * Rn; idx += 128)
        trS[idx >> 4][idx & 15] = tr_w[idx];

    const f32x4 z4 = {0.f, 0.f, 0.f, 0.f};
    f32x4 accP[4] = {z4, z4, z4, z4};
    f32x4 accG = z4;

    for (int kc = 0; kc < Dn / KCH; ++kc) {
        const int k0 = kc * KCH;
        __syncthreads();

        // ---- stage A fragments: conv + hi/lo split
        {
            const int m  = tid & 31;
            const int s  = tid >> 5;
            const int t  = t0 + m;
            const int gk = k0 + 8 * s;
            float v[4][8];
            #pragma unroll
            for (int dr = 0; dr < 4; ++dr) {
                int tp = t - 3 + dr;
                if (tp >= 0) {
                    float4 a  = *(const float4*)&xb[(size_t)tp * Dn + gk];
                    float4 bq = *(const float4*)&xb[(size_t)tp * Dn + gk + 4];
                    v[dr][0]=a.x;  v[dr][1]=a.y;  v[dr][2]=a.z;  v[dr][3]=a.w;
                    v[dr][4]=bq.x; v[dr][5]=bq.y; v[dr][6]=bq.z; v[dr][7]=bq.w;
                } else {
                    #pragma unroll
                    for (int k = 0; k < 8; ++k) v[dr][k] = 0.f;
                }
            }
            bf16x8 fch, fcl, frh, frl;
            #pragma unroll
            for (int k = 0; k < 8; ++k) {
                float4 cw = *(const float4*)&conv_w[(size_t)(gk + k) * 4];
                float xr = v[3][k];
                float xc = xr;
                xc = fmaf(v[0][k], cw.x, xc);
                xc = fmaf(v[1][k], cw.y, xc);
                xc = fmaf(v[2][k], cw.z, xc);
                xc = fmaf(v[3][k], cw.w, xc);
                unsigned short h; float hf;
                h = bf16_rne(xc); hf = __uint_as_float((unsigned)h << 16);
                fch[k] = (short)h; fcl[k] = (short)bf16_rne(xc - hf);
                h = bf16_rne(xr); hf = __uint_as_float((unsigned)h << 16);
                frh[k] = (short)h; frl[k] = (short)bf16_rne(xr - hf);
            }
            const int lane = (m & 15) | (s << 4), mt = m >> 4;
            Axc_h[mt][lane] = fch; Axc_l[mt][lane] = fcl;
            Axr_h[mt][lane] = frh; Axr_l[mt][lane] = frl;
        }
        // ---- stage B fragments
        #pragma unroll
        for (int rep = 0; rep < 2; ++rep) {
            int slot = tid + rep * 128;
            int n = slot & 63, s = slot >> 6;
            const float* wp = &in_w[(size_t)n * Dn + k0 + 8 * s];
            float4 a  = *(const float4*)wp;
            float4 bq = *(const float4*)(wp + 4);
            float wv[8] = {a.x, a.y, a.z, a.w, bq.x, bq.y, bq.z, bq.w};
            bf16x8 fh, fl;
            #pragma unroll
            for (int k = 0; k < 8; ++k) {
                unsigned short h = bf16_rne(wv[k]);
                float hf = __uint_as_float((unsigned)h << 16);
                fh[k] = (short)h; fl[k] = (short)bf16_rne(wv[k] - hf);
            }
            Bw_h[n >> 4][(n & 15) | (s << 4)] = fh;
            Bw_l[n >> 4][(n & 15) | (s << 4)] = fl;
        }
        if (tid < 64) {
            int r = tid & 15, s = tid >> 4;
            const float* wp = &dt_w[(size_t)r * Dn + k0 + 8 * s];
            float4 a  = *(const float4*)wp;
            float4 bq = *(const float4*)(wp + 4);
            float wv[8] = {a.x, a.y, a.z, a.w, bq.x, bq.y, bq.z, bq.w};
            bf16x8 fh, fl;
            #pragma unroll
            for (int k = 0; k < 8; ++k) {
                unsigned short h = bf16_rne(wv[k]);
                float hf = __uint_as_float((unsigned)h << 16);
                fh[k] = (short)h; fl[k] = (short)bf16_rne(wv[k] - hf);
            }
            Bd_h[tid] = fh; Bd_l[tid] = fl;
        }
        __syncthreads();

        // ---- MFMA phase: bf16x3 = Ah*Bh + Al*Bh + Ah*Bl
        bf16x8 axh = Axc_h[w][l], axl = Axc_l[w][l];
        bf16x8 arh = Axr_h[w][l], arl = Axr_l[w][l];
        #pragma unroll
        for (int nt = 0; nt < 4; ++nt) {
            bf16x8 bh = Bw_h[nt][l], bl = Bw_l[nt][l];
            accP[nt] = __builtin_amdgcn_mfma_f32_16x16x32_bf16(axh, bh, accP[nt], 0, 0, 0);
            accP[nt] = __builtin_amdgcn_mfma_f32_16x16x32_bf16(axl, bh, accP[nt], 0, 0, 0);
            accP[nt] = __builtin_amdgcn_mfma_f32_16x16x32_bf16(axh, bl, accP[nt], 0, 0, 0);
        }
        {
            bf16x8 bh = Bd_h[l], bl = Bd_l[l];
            accG = __builtin_amdgcn_mfma_f32_16x16x32_bf16(arh, bh, accG, 0, 0, 0);
            accG = __builtin_amdgcn_mfma_f32_16x16x32_bf16(arl, bh, accG, 0, 0, 0);
            accG = __builtin_amdgcn_mfma_f32_16x16x32_bf16(arh, bl, accG, 0, 0, 0);
        }
    }

    // ---- epilogue: As = tanh(G + dt_b); Dl = As @ tr_w.T; write P, Dl
    __syncthreads();
    #pragma unroll
    for (int i = 0; i < 4; ++i)
        AsS[16 * w + 4 * (l >> 4) + i][l & 15] = tanhf(accG[i] + dt_b[l & 15]);
    __syncthreads();

    float as_[4][16];
    #pragma unroll
    for (int i = 0; i < 4; ++i) {
        int mrow = 16 * w + 4 * (l >> 4) + i;
        #pragma unroll
        for (int j = 0; j < 4; ++j) {
            float4 q = *(const float4*)&AsS[mrow][4 * j];
            as_[i][4*j] = q.x; as_[i][4*j+1] = q.y;
            as_[i][4*j+2] = q.z; as_[i][4*j+3] = q.w;
        }
    }
    const int tile0 = t0 & ~63;        // 64-aligned tile base (t0 is 0 or 32 mod 64)
    const int coff  = t0 & 63;         // col offset of this block's 32 rows
    #pragma unroll
    for (int nt = 0; nt < 4; ++nt) {
        int n = 16 * nt + (l & 15);
        float tw[16];
        #pragma unroll
        for (int j = 0; j < 4; ++j) {
            float4 q = *(const float4*)&trS[n][4 * j];
            tw[4*j] = q.x; tw[4*j+1] = q.y; tw[4*j+2] = q.z; tw[4*j+3] = q.w;
        }
        float ib = in_b[n];
        #pragma unroll
        for (int i = 0; i < 4; ++i) {
            int mrow = 16 * w + 4 * (l >> 4) + i;
            float dlv = 0.f;
            #pragma unroll
            for (int r = 0; r < 16; ++r) dlv = fmaf(as_[i][r], tw[r], dlv);
            // transposed write: row = tile0 + n, col = coff + mrow
            size_t a = ((size_t)(b * Tn + tile0 + n)) * Dn + coff + mrow;
            O[a]      = accP[nt][i] + ib;
            O[a + 64] = dlv;
        }
    }
}

// ---------------------------------------------------------------------------
// Kernel 2: sequential scan over transposed layout. grid (B), block 64.
// Lane n owns chain n; its P/Dl/S data is contiguous over t within each
// 64-tile -> float4 register prefetch, pinned by an asm scheduling fence.
// ---------------------------------------------------------------------------
__global__ __launch_bounds__(64, 1)
void scan_kernel(float* __restrict__ O)
{
    const int b = blockIdx.x;
    const int n = threadIdx.x;
    float* obase = O + (size_t)b * Tn * Dn;

    const float L2E = 1.44269504088896340736f;

    f32x4 pc[8], dc[8];
    {   // chunk 0: tile 0, cols [0,32)
        float* p0 = obase + (size_t)n * Dn;
        #pragma unroll
        for (int j = 0; j < 8; ++j) {
            pc[j] = *(const f32x4*)(p0 + 4 * j);
            dc[j] = *(const f32x4*)(p0 + 64 + 4 * j);
        }
    }

    float st = 0.f;
    for (int t0 = 0; t0 < Tn; t0 += SU) {
        f32x4 pn[8], dn[8];
        const bool more = (t0 + SU) < Tn;
        if (more) {
            const int tn = t0 + SU;
            float* np = obase + (size_t)((tn & ~63) + n) * Dn + (tn & 63);
            #pragma unroll
            for (int j = 0; j < 8; ++j) {
                pn[j] = *(const f32x4*)(np + 4 * j);
                dn[j] = *(const f32x4*)(np + 64 + 4 * j);
            }
        }
        asm volatile("" ::: "memory");   // pin prefetch issue before compute

        float* cp = obase + (size_t)((t0 & ~63) + n) * Dn + (t0 & 63);
        #pragma unroll
        for (int j = 0; j < 8; ++j) {
            #pragma unroll
            for (int i = 0; i < 4; ++i) {
                float d  = dc[j][i];
                float dL = d * L2E;
                float u  = st + d;
                float e  = __builtin_amdgcn_exp2f(fmaf(st, -L2E, -dL));
                float r  = __builtin_amdgcn_rcpf(1.f + e);
                st = fmaf(u, r, pc[j][i]);
                pc[j][i] = st;               // reuse as store buffer
            }
            *(f32x4*)(cp + 128 + 4 * j) = pc[j];
        }
        if (more) {
            #pragma unroll
            for (int j = 0; j < 8; ++j) { pc[j] = pn[j]; dc[j] = dn[j]; }
        }
    }
}

// ---------------------------------------------------------------------------
// Kernel 3: output projection, in-place. grid (BT/64), block 256.
// S is stored transposed in this block's rows; staging un-transposes to LDS.
// ---------------------------------------------------------------------------
__global__ __launch_bounds__(256)
void out_kernel(const float* __restrict__ out_w, const float* __restrict__ out_b,
                float* __restrict__ O)
{
    __shared__ float Ss[64][Nn + 4];   // Ss[t_local][n]
    __shared__ float wT[Nn][64 + 4];

    const int tid = threadIdx.x;
    const int r0  = blockIdx.x * 64;
    const int c   = tid & 15;
    const int g   = tid >> 4;

    // stage S: element (t = r0+tl, n) lives at O[(r0+n)*Dn + 128 + tl]
    for (int idx = tid; idx < 64 * 16; idx += 256) {
        int nn = idx >> 4, tg = idx & 15;
        float4 v = *(const float4*)&O[(size_t)(r0 + nn) * Dn + 128 + 4 * tg];
        Ss[4 * tg + 0][nn] = v.x;
        Ss[4 * tg + 1][nn] = v.y;
        Ss[4 * tg + 2][nn] = v.z;
        Ss[4 * tg + 3][nn] = v.w;
    }
    __syncthreads();

    for (int cb = 0; cb < Dn / 64; ++cb) {
        const int d0 = cb * 64;
        for (int idx = tid; idx < Nn * 64 / 4; idx += 256) {
            int dl = idx >> 4, n4 = (idx & 15) * 4;
            float4 wv = *(const float4*)&out_w[(size_t)(d0 + dl) * Nn + n4];
            wT[n4 + 0][dl] = wv.x;
            wT[n4 + 1][dl] = wv.y;
            wT[n4 + 2][dl] = wv.z;
            wT[n4 + 3][dl] = wv.w;
        }
        __syncthreads();

        float acc[4][4] = {};
        #pragma unroll
        for (int kq = 0; kq < Nn; kq += 4) {
            float4 wv0 = *(const float4*)&wT[kq + 0][4 * c];
            float4 wv1 = *(const float4*)&wT[kq + 1][4 * c];
            float4 wv2 = *(const float4*)&wT[kq + 2][4 * c];
            float4 wv3 = *(const float4*)&wT[kq + 3][4 * c];
            #pragma unroll
            for (int i = 0; i < 4; ++i) {
                int row = g + 16 * i;
                float4 xv = *(const float4*)&Ss[row][kq];
                acc[i][0] = fmaf(xv.x, wv0.x, fmaf(xv.y, wv1.x, fmaf(xv.z, wv2.x, fmaf(xv.w, wv3.x, acc[i][0]))));
                acc[i][1] = fmaf(xv.x, wv0.y, fmaf(xv.y, wv1.y, fmaf(xv.z, wv2.y, fmaf(xv.w, wv3.y, acc[i][1]))));
                acc[i][2] = fmaf(xv.x, wv0.z, fmaf(xv.y, wv1.z, fmaf(xv.z, wv2.z, fmaf(xv.w, wv3.z, acc[i][2]))));
                acc[i][3] = fmaf(xv.x, wv0.w, fmaf(xv.y, wv1.w, fmaf(xv.z, wv2.w, fmaf(xv.w, wv3.w, acc[i][3]))));
            }
        }

        float4 bb = *(const float4*)&out_b[d0 + 4 * c];
        #pragma unroll
        for (int i = 0; i < 4; ++i) {
            int row = g + 16 * i;
            float4 o = make_float4(acc[i][0] + bb.x, acc[i][1] + bb.y,
                                   acc[i][2] + bb.z, acc[i][3] + bb.w);
            *(float4*)&O[(size_t)(r0 + row) * Dn + d0 + 4 * c] = o;
        }
        __syncthreads();
    }
}

extern "C" void kernel_launch(void* const* d_in, const int* in_sizes, int n_in,
                              void* d_out, int out_size, void* d_ws, size_t ws_size,
                              hipStream_t stream)
{
    const float* x      = (const float*)d_in[0];
    const float* conv_w = (const float*)d_in[1];
    const float* in_w   = (const float*)d_in[2];
    const float* in_b   = (const float*)d_in[3];
    const float* dt_w   = (const float*)d_in[4];
    const float* dt_b   = (const float*)d_in[5];
    const float* tr_w   = (const float*)d_in[6];
    const float* out_w  = (const float*)d_in[7];
    const float* out_b  = (const float*)d_in[8];
    float* O = (float*)d_out;
    (void)d_ws; (void)ws_size;

    dim3 g1(Tn / TT2, Bn);
    prep_kernel<<<g1, 128, 0, stream>>>(x, conv_w, in_w, in_b, dt_w, dt_b, tr_w, O);

    scan_kernel<<<dim3(Bn), 64, 0, stream>>>(O);

    out_kernel<<<dim3((Bn * Tn) / 64), 256, 0, stream>>>(out_w, out_b, O);
}